// Round 10
// baseline (177.803 us; speedup 1.0000x reference)
//
#include <hip/hip_runtime.h>
#include <stdint.h>

#define NR 8192
#define DIM 512
#define BT 256             // block tile M=N
#define BK 64              // K-tile (128 B rows, 8 x 16B chunks)
#define NT (DIM / BK)      // 8 K-tiles

typedef unsigned short u16;
typedef __attribute__((ext_vector_type(8))) __bf16 bf16x8;
typedef __attribute__((ext_vector_type(4))) float f32x4;

static __device__ __forceinline__ u16 f2bf(float f) {
    union { float f; uint32_t u; } v; v.f = f;
    uint32_t u = v.u;
    u += 0x7FFFu + ((u >> 16) & 1u);   // RNE
    return (u16)(u >> 16);
}

static __device__ __forceinline__ void gload_lds16(const void* g, void* l) {
    __builtin_amdgcn_global_load_lds(
        (__attribute__((address_space(1))) void*)(void*)g,
        (__attribute__((address_space(3))) void*)l,
        16, 0, 0);
}

// One block per row: reciprocal norms, exact fp32 diag term, fp32->bf16
// conversion, and zero rowsum for this call.
__global__ void prep_kernel(const float* __restrict__ xi, const float* __restrict__ xj,
                            u16* __restrict__ xib, u16* __restrict__ xjb,
                            float* __restrict__ inv_ni, float* __restrict__ inv_nj,
                            float* __restrict__ diag, float* __restrict__ rowsum) {
    const int row = blockIdx.x;
    const int t = threadIdx.x;                 // 128 threads, 4 elems each
    const float4 a = ((const float4*)(xi + (size_t)row * DIM))[t];
    const float4 b = ((const float4*)(xj + (size_t)row * DIM))[t];

    float ssi = a.x*a.x + a.y*a.y + a.z*a.z + a.w*a.w;
    float ssj = b.x*b.x + b.y*b.y + b.z*b.z + b.w*b.w;
    float dot = a.x*b.x + a.y*b.y + a.z*b.z + a.w*b.w;

    ushort4 av = { f2bf(a.x), f2bf(a.y), f2bf(a.z), f2bf(a.w) };
    ushort4 bv = { f2bf(b.x), f2bf(b.y), f2bf(b.z), f2bf(b.w) };
    ((ushort4*)(xib + (size_t)row * DIM))[t] = av;
    ((ushort4*)(xjb + (size_t)row * DIM))[t] = bv;

    #pragma unroll
    for (int m = 32; m >= 1; m >>= 1) {
        ssi += __shfl_xor(ssi, m, 64);
        ssj += __shfl_xor(ssj, m, 64);
        dot += __shfl_xor(dot, m, 64);
    }
    __shared__ float red[6];
    const int wave = t >> 6, lane = t & 63;
    if (lane == 0) { red[wave*3+0] = ssi; red[wave*3+1] = ssj; red[wave*3+2] = dot; }
    __syncthreads();
    if (t == 0) {
        float si = red[0] + red[3];
        float sj = red[1] + red[4];
        float d  = red[2] + red[5];
        float ini = rsqrtf(fmaxf(si, 1e-30f));
        float inj = rsqrtf(fmaxf(sj, 1e-30f));
        inv_ni[row] = ini;
        inv_nj[row] = inj;
        diag[row] = d * ini * inj;
        rowsum[row] = 0.0f;
    }
}

// Fused NT-GEMM + exp + row-sum. Round-7 loop structure (simple 2-barrier,
// TLP-hidden latency, proven 2-way chunk swizzle) at 2x arithmetic
// intensity: 256x256 block, 4 waves (2x2), wave tile 128x128 of 16x16x32
// frags (acc 8x8 f32x4 = 256 regs), BK=64, 64 KB LDS single-buffered,
// 2 blocks/CU. Per tile per wave: 32 ds_read_b128 -> 128 MFMA (1:4).
__global__ __launch_bounds__(256, 1)
void gemm_rowsum(const u16* __restrict__ A, const u16* __restrict__ B,
                 const float* __restrict__ inv_ni, const float* __restrict__ inv_nj,
                 float* __restrict__ rowsum) {
    __shared__ __align__(16) u16 ldsA[BT * BK];   // 32 KB
    __shared__ __align__(16) u16 ldsB[BT * BK];   // 32 KB

    const int tid = threadIdx.x;
    // XCD-aware: xcd owns 4 row-panels x 32 col-panels, ordered by-fastest;
    // concurrent-per-XCD working set ~4 row x 16 col panels (L3 backstops).
    const int orig = blockIdx.x;                  // 0..1023
    const int xcd = orig & 7, kidx = orig >> 3;   // kidx 0..127
    const int by = xcd * 4 + (kidx & 3);          // 0..31
    const int bx = kidx >> 2;                     // 0..31
    const int row0 = by * BT, col0 = bx * BT;

    // ---- staging: thread t -> pass i covers row (i*32 + (t>>3)), chunk t&7 ----
    // LDS byte = i*4096 + tid*16 (linear); global logical chunk = phys ^ (row&7)
    // (row&7 invariant across passes since 32 % 8 == 0).
    const int st_row = tid >> 3;                        // 0..31
    const int st_lc  = (tid & 7) ^ (st_row & 7);        // logical 16B k-chunk
    const u16* gA = A + (size_t)(row0 + st_row) * DIM + st_lc * 8;
    const u16* gB = B + (size_t)(col0 + st_row) * DIM + st_lc * 8;
    char* const dA = (char*)ldsA + tid * 16;
    char* const dB = (char*)ldsB + tid * 16;

    // ---- fragment reads (16x16x32, round-7 verified 2-way pattern) ----
    const int lane = tid & 63;
    const int lr = lane & 15, lk = lane >> 4, sw = lr & 7;
    const int wid = tid >> 6;
    const int wm = wid >> 1, wn = wid & 1;              // 2x2 waves, 128x128 tile
    // frag m: row = wm*128 + m*16 + lr  (row&7 == lr&7); chunk = kk*4 + lk
    const char* const aR = (const char*)ldsA + (wm * 128 + lr) * 128;
    const char* const bR = (const char*)ldsB + (wn * 128 + lr) * 128;

    f32x4 acc[8][8] = {};

    #pragma unroll 1
    for (int t = 0; t < NT; ++t) {
        if (t) __syncthreads();               // prev tile's reads complete
        #pragma unroll
        for (int i = 0; i < 8; ++i) {         // 16 x global_load_lds_dwordx4
            gload_lds16(gA + t * BK + i * 32 * DIM, dA + i * 4096);
            gload_lds16(gB + t * BK + i * 32 * DIM, dB + i * 4096);
        }
        __syncthreads();                      // drains vmcnt; TLP fills stall

        #pragma unroll
        for (int kk = 0; kk < 2; ++kk) {
            const int cb = ((kk * 4 + lk) ^ sw) * 16;
            bf16x8 af[8], bg[8];
            #pragma unroll
            for (int m = 0; m < 8; ++m)
                af[m] = *(const bf16x8*)(aR + m * 2048 + cb);
            #pragma unroll
            for (int n = 0; n < 8; ++n)
                bg[n] = *(const bf16x8*)(bR + n * 2048 + cb);
            #pragma unroll
            for (int m = 0; m < 8; ++m)
                #pragma unroll
                for (int n = 0; n < 8; ++n)
                    acc[m][n] = __builtin_amdgcn_mfma_f32_16x16x32_bf16(
                        af[m], bg[n], acc[m][n], 0, 0, 0);
        }
    }

    // ---- epilogue: cosine scale, exp, row-reduce, one atomic per row ----
    float inj[8];
    #pragma unroll
    for (int n = 0; n < 8; ++n)
        inj[n] = inv_nj[col0 + wn * 128 + n * 16 + lr];

    #pragma unroll
    for (int m = 0; m < 8; ++m) {
        #pragma unroll
        for (int e = 0; e < 4; ++e) {
            const int row = row0 + wm * 128 + m * 16 + lk * 4 + e;
            const float ini = inv_ni[row];
            float s = 0.0f;
            #pragma unroll
            for (int n = 0; n < 8; ++n)
                s += __expf(acc[m][n][e] * ini * inj[n]);
            s += __shfl_xor(s, 1, 64);
            s += __shfl_xor(s, 2, 64);
            s += __shfl_xor(s, 4, 64);
            s += __shfl_xor(s, 8, 64);
            if (lr == 0)
                atomicAdd(&rowsum[row], s);
        }
    }
}

__global__ void finalize(const float* __restrict__ rowsum,
                         const float* __restrict__ diag,
                         float* __restrict__ out) {
    const float E1 = 2.7182818284590452f;  // exp(1/TAU)
    float acc = 0.0f;
    for (int i = threadIdx.x; i < NR; i += 256)
        acc += __logf(rowsum[i] - E1) - diag[i];
    #pragma unroll
    for (int m = 32; m >= 1; m >>= 1)
        acc += __shfl_xor(acc, m, 64);
    __shared__ float red[4];
    const int wave = threadIdx.x >> 6, lane = threadIdx.x & 63;
    if (lane == 0) red[wave] = acc;
    __syncthreads();
    if (threadIdx.x == 0)
        out[0] = (red[0] + red[1] + red[2] + red[3]) * (1.0f / NR);
}

extern "C" void kernel_launch(void* const* d_in, const int* in_sizes, int n_in,
                              void* d_out, int out_size, void* d_ws, size_t ws_size,
                              hipStream_t stream) {
    const float* xi = (const float*)d_in[0];
    const float* xj = (const float*)d_in[1];

    char* ws = (char*)d_ws;
    u16* xib = (u16*)ws;                                // 8 MB
    u16* xjb = xib + (size_t)NR * DIM;                  // 8 MB
    float* inv_ni = (float*)(xjb + (size_t)NR * DIM);   // 32 KB
    float* inv_nj = inv_ni + NR;
    float* diag   = inv_nj + NR;
    float* rowsum = diag + NR;

    prep_kernel<<<NR, 128, 0, stream>>>(xi, xj, xib, xjb, inv_ni, inv_nj, diag, rowsum);
    gemm_rowsum<<<(NR / BT) * (NR / BT), 256, 0, stream>>>(xib, xjb, inv_ni, inv_nj, rowsum);
    finalize<<<1, 256, 0, stream>>>(rowsum, diag, (float*)d_out);
}

// Round 11
// 176.120 us; speedup vs baseline: 1.0096x; 1.0096x over previous
//
#include <hip/hip_runtime.h>
#include <stdint.h>

#define NR 8192
#define DIM 512
#define BT 128             // block tile M=N
#define BK 64              // K-tile (A rows in LDS are 128 B = 8 x 16B chunks)
#define NT (DIM / BK)      // 8 K-tiles

typedef unsigned short u16;
typedef __attribute__((ext_vector_type(8))) __bf16 bf16x8;
typedef __attribute__((ext_vector_type(4))) float f32x4;

static __device__ __forceinline__ u16 f2bf(float f) {
    union { float f; uint32_t u; } v; v.f = f;
    uint32_t u = v.u;
    u += 0x7FFFu + ((u >> 16) & 1u);   // RNE
    return (u16)(u >> 16);
}

static __device__ __forceinline__ void gload_lds16(const void* g, void* l) {
    __builtin_amdgcn_global_load_lds(
        (__attribute__((address_space(1))) void*)(void*)g,
        (__attribute__((address_space(3))) void*)l,
        16, 0, 0);
}

// One block per row: reciprocal norms, exact fp32 diag term, fp32->bf16
// conversion, and zero rowsum for this call.
__global__ void prep_kernel(const float* __restrict__ xi, const float* __restrict__ xj,
                            u16* __restrict__ xib, u16* __restrict__ xjb,
                            float* __restrict__ inv_ni, float* __restrict__ inv_nj,
                            float* __restrict__ diag, float* __restrict__ rowsum) {
    const int row = blockIdx.x;
    const int t = threadIdx.x;                 // 128 threads, 4 elems each
    const float4 a = ((const float4*)(xi + (size_t)row * DIM))[t];
    const float4 b = ((const float4*)(xj + (size_t)row * DIM))[t];

    float ssi = a.x*a.x + a.y*a.y + a.z*a.z + a.w*a.w;
    float ssj = b.x*b.x + b.y*b.y + b.z*b.z + b.w*b.w;
    float dot = a.x*b.x + a.y*b.y + a.z*b.z + a.w*b.w;

    ushort4 av = { f2bf(a.x), f2bf(a.y), f2bf(a.z), f2bf(a.w) };
    ushort4 bv = { f2bf(b.x), f2bf(b.y), f2bf(b.z), f2bf(b.w) };
    ((ushort4*)(xib + (size_t)row * DIM))[t] = av;
    ((ushort4*)(xjb + (size_t)row * DIM))[t] = bv;

    #pragma unroll
    for (int m = 32; m >= 1; m >>= 1) {
        ssi += __shfl_xor(ssi, m, 64);
        ssj += __shfl_xor(ssj, m, 64);
        dot += __shfl_xor(dot, m, 64);
    }
    __shared__ float red[6];
    const int wave = t >> 6, lane = t & 63;
    if (lane == 0) { red[wave*3+0] = ssi; red[wave*3+1] = ssj; red[wave*3+2] = dot; }
    __syncthreads();
    if (t == 0) {
        float si = red[0] + red[3];
        float sj = red[1] + red[4];
        float d  = red[2] + red[5];
        float ini = rsqrtf(fmaxf(si, 1e-30f));
        float inj = rsqrtf(fmaxf(sj, 1e-30f));
        inv_ni[row] = ini;
        inv_nj[row] = inj;
        diag[row] = d * ini * inj;
        rowsum[row] = 0.0f;
    }
}

// Fused NT-GEMM + exp + row-sum, flatmm style:
//   A: double-buffered LDS (2 x 16 KB), proven 2-way chunk swizzle.
//   B: streamed L2 -> registers (no LDS, no barrier coupling); lanes
//      lk=0..3 of a row read one 64B segment (coalesced); B panel is
//      L2-hot under the XCD map and reused by ~8 row-blocks per XCD.
// One barrier per K-tile: STAGE(t+1) -> B loads -> compute(t) ->
// vmcnt(0) -> s_barrier. Buffer p's tile-t reads are register-consumed
// before the tile-t barrier; p is overwritten at t+1 after it.
__global__ __launch_bounds__(256, 3)
void gemm_rowsum(const u16* __restrict__ A, const u16* __restrict__ B,
                 const float* __restrict__ inv_ni, const float* __restrict__ inv_nj,
                 float* __restrict__ rowsum) {
    __shared__ __align__(16) u16 ldsA[2][BT * BK];   // 32 KB

    const int tid = threadIdx.x;
    // XCD-aware, L2-aware: xcd owns 8 row-panels; concurrent ~96 blocks/XCD
    // cover 8 row-panels x ~12 col-panels: A 1MB staged + B ~1.5MB < 4MB L2.
    const int orig = blockIdx.x;
    const int xcd = orig & 7, kidx = orig >> 3;   // kidx 0..511
    const int by = xcd * 8 + (kidx & 7);          // 0..63
    const int bx = kidx >> 3;                     // 0..63
    const int row0 = by * BT, col0 = bx * BT;

    // ---- A staging: pass i covers row (i*32 + (tid>>3)), phys chunk tid&7 ----
    // LDS byte = i*4096 + tid*16 (linear); global logical chunk = phys ^ (row&7)
    const int st_row = tid >> 3;                        // 0..31
    const int st_lc  = (tid & 7) ^ (st_row & 7);        // logical 16B k-chunk
    const u16* gA = A + (size_t)(row0 + st_row) * DIM + st_lc * 8;
    char* const dA = (char*)ldsA + tid * 16;

    // ---- fragment addressing ----
    const int lane = tid & 63;
    const int lr = lane & 15, lk = lane >> 4, sw = lr & 7;
    const int wid = tid >> 6;
    const int wm = wid >> 1, wn = wid & 1;              // 2x2 waves, 64x64 tile
    const char* const aR0 = (const char*)ldsA + (wm * 64 + lr) * 128;
    const int cb0 = (lk ^ sw) * 16;                     // kk=0 phys byte
    const int cb1 = ((4 + lk) ^ sw) * 16;               // kk=1 phys byte
    // B direct: lane reads row col0 + wn*64 + n*16 + lr, k bytes lk*16 within
    // each 64B span; per-tile offset t*BK, kk offset 32 elems.
    const u16* const gB = B + (size_t)(col0 + wn * 64 + lr) * DIM + lk * 8;

    f32x4 acc[4][4] = {};

#define STAGE(P, TN) do {                                                      \
    _Pragma("unroll") for (int i = 0; i < 4; ++i)                              \
        gload_lds16(gA + (TN) * BK + i * 32 * DIM, dA + (P) * 16384 + i * 4096); \
} while (0)

    // ---- prologue: stage tile 0 into buf 0 ----
    STAGE(0, 0);
    asm volatile("s_waitcnt vmcnt(0)" ::: "memory");
    __builtin_amdgcn_s_barrier();

    #pragma unroll 1
    for (int t = 0; t < NT; ++t) {
        const int p = t & 1;
        if (t < NT - 1) STAGE(p ^ 1, t + 1);

        const u16* gBt = gB + t * BK;
        const char* aR = aR0 + p * 16384;

        // kk = 0
        bf16x8 bg[4], af[4];
        #pragma unroll
        for (int n = 0; n < 4; ++n)
            bg[n] = *(const bf16x8*)(gBt + n * 16 * DIM);
        #pragma unroll
        for (int m = 0; m < 4; ++m)
            af[m] = *(const bf16x8*)(aR + m * 2048 + cb0);
        #pragma unroll
        for (int m = 0; m < 4; ++m)
            #pragma unroll
            for (int n = 0; n < 4; ++n)
                acc[m][n] = __builtin_amdgcn_mfma_f32_16x16x32_bf16(
                    af[m], bg[n], acc[m][n], 0, 0, 0);

        // kk = 1
        #pragma unroll
        for (int n = 0; n < 4; ++n)
            bg[n] = *(const bf16x8*)(gBt + n * 16 * DIM + 32);
        #pragma unroll
        for (int m = 0; m < 4; ++m)
            af[m] = *(const bf16x8*)(aR + m * 2048 + cb1);
        #pragma unroll
        for (int m = 0; m < 4; ++m)
            #pragma unroll
            for (int n = 0; n < 4; ++n)
                acc[m][n] = __builtin_amdgcn_mfma_f32_16x16x32_bf16(
                    af[m], bg[n], acc[m][n], 0, 0, 0);

        if (t < NT - 1) {
            // next tile's A staged long ago; wait is cheap, then one barrier
            asm volatile("s_waitcnt vmcnt(0)" ::: "memory");
            __builtin_amdgcn_s_barrier();
        }
    }
#undef STAGE

    // ---- epilogue: cosine scale, exp, row-reduce, one atomic per row ----
    float inj[4];
    #pragma unroll
    for (int n = 0; n < 4; ++n)
        inj[n] = inv_nj[col0 + wn * 64 + n * 16 + lr];

    #pragma unroll
    for (int m = 0; m < 4; ++m) {
        #pragma unroll
        for (int e = 0; e < 4; ++e) {
            const int row = row0 + wm * 64 + m * 16 + lk * 4 + e;
            const float ini = inv_ni[row];
            float s = 0.0f;
            #pragma unroll
            for (int n = 0; n < 4; ++n)
                s += __expf(acc[m][n][e] * ini * inj[n]);
            s += __shfl_xor(s, 1, 64);
            s += __shfl_xor(s, 2, 64);
            s += __shfl_xor(s, 4, 64);
            s += __shfl_xor(s, 8, 64);
            if (lr == 0)
                atomicAdd(&rowsum[row], s);
        }
    }
}

__global__ void finalize(const float* __restrict__ rowsum,
                         const float* __restrict__ diag,
                         float* __restrict__ out) {
    const float E1 = 2.7182818284590452f;  // exp(1/TAU)
    float acc = 0.0f;
    for (int i = threadIdx.x; i < NR; i += 256)
        acc += __logf(rowsum[i] - E1) - diag[i];
    #pragma unroll
    for (int m = 32; m >= 1; m >>= 1)
        acc += __shfl_xor(acc, m, 64);
    __shared__ float red[4];
    const int wave = threadIdx.x >> 6, lane = threadIdx.x & 63;
    if (lane == 0) red[wave] = acc;
    __syncthreads();
    if (threadIdx.x == 0)
        out[0] = (red[0] + red[1] + red[2] + red[3]) * (1.0f / NR);
}

extern "C" void kernel_launch(void* const* d_in, const int* in_sizes, int n_in,
                              void* d_out, int out_size, void* d_ws, size_t ws_size,
                              hipStream_t stream) {
    const float* xi = (const float*)d_in[0];
    const float* xj = (const float*)d_in[1];

    char* ws = (char*)d_ws;
    u16* xib = (u16*)ws;                                // 8 MB
    u16* xjb = xib + (size_t)NR * DIM;                  // 8 MB
    float* inv_ni = (float*)(xjb + (size_t)NR * DIM);   // 32 KB
    float* inv_nj = inv_ni + NR;
    float* diag   = inv_nj + NR;
    float* rowsum = diag + NR;

    prep_kernel<<<NR, 128, 0, stream>>>(xi, xj, xib, xjb, inv_ni, inv_nj, diag, rowsum);
    gemm_rowsum<<<(NR / BT) * (NR / BT), 256, 0, stream>>>(xib, xjb, inv_ni, inv_nj, rowsum);
    finalize<<<1, 256, 0, stream>>>(rowsum, diag, (float*)d_out);
}

// Round 13
// 172.654 us; speedup vs baseline: 1.0298x; 1.0201x over previous
//
#include <hip/hip_runtime.h>
#include <stdint.h>

#define NR 8192
#define DIM 512
#define BT 128             // block tile M=N
#define BK 64              // K-tile (A rows in LDS are 128 B = 8 x 16B chunks)
#define NT (DIM / BK)      // 8 K-tiles

typedef unsigned short u16;
typedef __attribute__((ext_vector_type(8))) __bf16 bf16x8;
typedef __attribute__((ext_vector_type(4))) float f32x4;

static __device__ __forceinline__ u16 f2bf(float f) {
    union { float f; uint32_t u; } v; v.f = f;
    uint32_t u = v.u;
    u += 0x7FFFu + ((u >> 16) & 1u);   // RNE
    return (u16)(u >> 16);
}

static __device__ __forceinline__ void gload_lds16(const void* g, void* l) {
    __builtin_amdgcn_global_load_lds(
        (__attribute__((address_space(1))) void*)(void*)g,
        (__attribute__((address_space(3))) void*)l,
        16, 0, 0);
}

// One block per row: reciprocal norms, exact fp32 diag term, fp32->bf16
// conversion, and zero rowsum for this call.
__global__ void prep_kernel(const float* __restrict__ xi, const float* __restrict__ xj,
                            u16* __restrict__ xib, u16* __restrict__ xjb,
                            float* __restrict__ inv_ni, float* __restrict__ inv_nj,
                            float* __restrict__ diag, float* __restrict__ rowsum) {
    const int row = blockIdx.x;
    const int t = threadIdx.x;                 // 128 threads, 4 elems each
    const float4 a = ((const float4*)(xi + (size_t)row * DIM))[t];
    const float4 b = ((const float4*)(xj + (size_t)row * DIM))[t];

    float ssi = a.x*a.x + a.y*a.y + a.z*a.z + a.w*a.w;
    float ssj = b.x*b.x + b.y*b.y + b.z*b.z + b.w*b.w;
    float dot = a.x*b.x + a.y*b.y + a.z*b.z + a.w*b.w;

    ushort4 av = { f2bf(a.x), f2bf(a.y), f2bf(a.z), f2bf(a.w) };
    ushort4 bv = { f2bf(b.x), f2bf(b.y), f2bf(b.z), f2bf(b.w) };
    ((ushort4*)(xib + (size_t)row * DIM))[t] = av;
    ((ushort4*)(xjb + (size_t)row * DIM))[t] = bv;

    #pragma unroll
    for (int m = 32; m >= 1; m >>= 1) {
        ssi += __shfl_xor(ssi, m, 64);
        ssj += __shfl_xor(ssj, m, 64);
        dot += __shfl_xor(dot, m, 64);
    }
    __shared__ float red[6];
    const int wave = t >> 6, lane = t & 63;
    if (lane == 0) { red[wave*3+0] = ssi; red[wave*3+1] = ssj; red[wave*3+2] = dot; }
    __syncthreads();
    if (t == 0) {
        float si = red[0] + red[3];
        float sj = red[1] + red[4];
        float d  = red[2] + red[5];
        float ini = rsqrtf(fmaxf(si, 1e-30f));
        float inj = rsqrtf(fmaxf(sj, 1e-30f));
        inv_ni[row] = ini;
        inv_nj[row] = inj;
        diag[row] = d * ini * inj;
        rowsum[row] = 0.0f;
    }
}

// Fused NT-GEMM + exp + row-sum, flatmm with cross-tile B prefetch and
// airtight sync:
//   A: double-buffered LDS (2 x 16 KB), proven 2-way chunk swizzle.
//   B: L2 -> registers; kk0 of tile t+1 prefetched at top of tile t
//      (parity-named bgN0/bgN1); kk1 of tile t loaded at tile top.
//   One __syncthreads() per tile: full drain + barrier with compiler
//   memory semantics (no hoist hazard). All drained loads were issued a
//   full tile earlier, so the drain is ~free; issue-early = latency cover.
__global__ __launch_bounds__(256, 3)
void gemm_rowsum(const u16* __restrict__ A, const u16* __restrict__ B,
                 const float* __restrict__ inv_ni, const float* __restrict__ inv_nj,
                 float* __restrict__ rowsum) {
    __shared__ __align__(16) u16 ldsA[2][BT * BK];   // 32 KB

    const int tid = threadIdx.x;
    // XCD-aware, L2-aware: xcd owns 8 row-panels; concurrent ~96 blocks/XCD
    // cover 8 row-panels x ~12 col-panels -> A+B hot in per-XCD L2.
    const int orig = blockIdx.x;
    const int xcd = orig & 7, kidx = orig >> 3;   // kidx 0..511
    const int by = xcd * 8 + (kidx & 7);          // 0..63
    const int bx = kidx >> 3;                     // 0..63
    const int row0 = by * BT, col0 = bx * BT;

    // ---- A staging: pass i covers row (i*32 + (tid>>3)), phys chunk tid&7 ----
    const int st_row = tid >> 3;                        // 0..31
    const int st_lc  = (tid & 7) ^ (st_row & 7);        // logical 16B k-chunk
    const u16* gA = A + (size_t)(row0 + st_row) * DIM + st_lc * 8;
    char* const dA = (char*)ldsA + tid * 16;

    // ---- fragment addressing ----
    const int lane = tid & 63;
    const int lr = lane & 15, lk = lane >> 4, sw = lr & 7;
    const int wid = tid >> 6;
    const int wm = wid >> 1, wn = wid & 1;              // 2x2 waves, 64x64 tile
    const char* const aR0 = (const char*)ldsA + (wm * 64 + lr) * 128;
    const int cb0 = (lk ^ sw) * 16;                     // kk=0 phys byte
    const int cb1 = ((4 + lk) ^ sw) * 16;               // kk=1 phys byte
    const u16* const gB = B + (size_t)(col0 + wn * 64 + lr) * DIM + lk * 8;

    f32x4 acc[4][4] = {};
    bf16x8 bgN0[4], bgN1[4], bgK1[4], af[4];

#define STAGE_A(P, TN) do {                                                    \
    _Pragma("unroll") for (int i = 0; i < 4; ++i)                              \
        gload_lds16(gA + (TN) * BK + i * 32 * DIM, dA + (P) * 16384 + i * 4096); \
} while (0)

#define LOADB(DST, TN, KOFF) do {                                              \
    _Pragma("unroll") for (int n = 0; n < 4; ++n)                              \
        DST[n] = *(const bf16x8*)(gB + (TN) * BK + (KOFF) + n * 16 * DIM);     \
} while (0)

#define TILE(T, P, ST, BGCUR, BGNXT) do {                                      \
    if (ST) STAGE_A((P) ^ 1, (T) + 1);            /* A(t+1): full-tile cover */\
    LOADB(bgK1, (T), 32);                         /* K1(t): kk0-block cover  */\
    if (ST) LOADB(BGNXT, (T) + 1, 0);             /* N(t+1): full-tile cover */\
    const char* aR = aR0 + (P) * 16384;                                        \
    _Pragma("unroll") for (int m = 0; m < 4; ++m)                              \
        af[m] = *(const bf16x8*)(aR + m * 2048 + cb0);                         \
    _Pragma("unroll") for (int m = 0; m < 4; ++m)                              \
        _Pragma("unroll") for (int n = 0; n < 4; ++n)                          \
            acc[m][n] = __builtin_amdgcn_mfma_f32_16x16x32_bf16(               \
                af[m], BGCUR[n], acc[m][n], 0, 0, 0);                          \
    _Pragma("unroll") for (int m = 0; m < 4; ++m)                              \
        af[m] = *(const bf16x8*)(aR + m * 2048 + cb1);                         \
    _Pragma("unroll") for (int m = 0; m < 4; ++m)                              \
        _Pragma("unroll") for (int n = 0; n < 4; ++n)                          \
            acc[m][n] = __builtin_amdgcn_mfma_f32_16x16x32_bf16(               \
                af[m], bgK1[n], acc[m][n], 0, 0, 0);                           \
    if (ST) __syncthreads();                      /* full drain + barrier */   \
} while (0)

    // ---- prologue: stage A tile 0, prefetch B(0,kk0) ----
    STAGE_A(0, 0);
    LOADB(bgN0, 0, 0);
    __syncthreads();

    TILE(0, 0, 1, bgN0, bgN1);
    TILE(1, 1, 1, bgN1, bgN0);
    TILE(2, 0, 1, bgN0, bgN1);
    TILE(3, 1, 1, bgN1, bgN0);
    TILE(4, 0, 1, bgN0, bgN1);
    TILE(5, 1, 1, bgN1, bgN0);
    TILE(6, 0, 1, bgN0, bgN1);
    TILE(7, 1, 0, bgN1, bgN0);

#undef STAGE_A
#undef LOADB
#undef TILE

    // ---- epilogue: cosine scale, exp, row-reduce, one atomic per row ----
    float inj[4];
    #pragma unroll
    for (int n = 0; n < 4; ++n)
        inj[n] = inv_nj[col0 + wn * 64 + n * 16 + lr];

    #pragma unroll
    for (int m = 0; m < 4; ++m) {
        #pragma unroll
        for (int e = 0; e < 4; ++e) {
            const int row = row0 + wm * 64 + m * 16 + lk * 4 + e;
            const float ini = inv_ni[row];
            float s = 0.0f;
            #pragma unroll
            for (int n = 0; n < 4; ++n)
                s += __expf(acc[m][n][e] * ini * inj[n]);
            s += __shfl_xor(s, 1, 64);
            s += __shfl_xor(s, 2, 64);
            s += __shfl_xor(s, 4, 64);
            s += __shfl_xor(s, 8, 64);
            if (lr == 0)
                atomicAdd(&rowsum[row], s);
        }
    }
}

__global__ void finalize(const float* __restrict__ rowsum,
                         const float* __restrict__ diag,
                         float* __restrict__ out) {
    const float E1 = 2.7182818284590452f;  // exp(1/TAU)
    float acc = 0.0f;
    for (int i = threadIdx.x; i < NR; i += 256)
        acc += __logf(rowsum[i] - E1) - diag[i];
    #pragma unroll
    for (int m = 32; m >= 1; m >>= 1)
        acc += __shfl_xor(acc, m, 64);
    __shared__ float red[4];
    const int wave = threadIdx.x >> 6, lane = threadIdx.x & 63;
    if (lane == 0) red[wave] = acc;
    __syncthreads();
    if (threadIdx.x == 0)
        out[0] = (red[0] + red[1] + red[2] + red[3]) * (1.0f / NR);
}

extern "C" void kernel_launch(void* const* d_in, const int* in_sizes, int n_in,
                              void* d_out, int out_size, void* d_ws, size_t ws_size,
                              hipStream_t stream) {
    const float* xi = (const float*)d_in[0];
    const float* xj = (const float*)d_in[1];

    char* ws = (char*)d_ws;
    u16* xib = (u16*)ws;                                // 8 MB
    u16* xjb = xib + (size_t)NR * DIM;                  // 8 MB
    float* inv_ni = (float*)(xjb + (size_t)NR * DIM);   // 32 KB
    float* inv_nj = inv_ni + NR;
    float* diag   = inv_nj + NR;
    float* rowsum = diag + NR;

    prep_kernel<<<NR, 128, 0, stream>>>(xi, xj, xib, xjb, inv_ni, inv_nj, diag, rowsum);
    gemm_rowsum<<<(NR / BT) * (NR / BT), 256, 0, stream>>>(xib, xjb, inv_ni, inv_nj, rowsum);
    finalize<<<1, 256, 0, stream>>>(rowsum, diag, (float*)d_out);
}

// Round 14
// 122.475 us; speedup vs baseline: 1.4517x; 1.4097x over previous
//
#include <hip/hip_runtime.h>
#include <stdint.h>

#define NR 8192
#define DIM 512
#define BM 128             // block tile M
#define BN 256             // block tile N
#define BK 64              // K-tile (LDS rows are 128 B = 8 x 16B chunks)
#define NT (DIM / BK)      // 8 K-tiles

typedef unsigned short u16;
typedef __attribute__((ext_vector_type(8))) __bf16 bf16x8;
typedef __attribute__((ext_vector_type(4))) float f32x4;

static __device__ __forceinline__ u16 f2bf(float f) {
    union { float f; uint32_t u; } v; v.f = f;
    uint32_t u = v.u;
    u += 0x7FFFu + ((u >> 16) & 1u);   // RNE
    return (u16)(u >> 16);
}

static __device__ __forceinline__ void gload_lds16(const void* g, void* l) {
    __builtin_amdgcn_global_load_lds(
        (__attribute__((address_space(1))) void*)(void*)g,
        (__attribute__((address_space(3))) void*)l,
        16, 0, 0);
}

// One block per row: reciprocal norms, exact fp32 diag term, fp32->bf16
// conversion, and zero rowsum for this call.
__global__ void prep_kernel(const float* __restrict__ xi, const float* __restrict__ xj,
                            u16* __restrict__ xib, u16* __restrict__ xjb,
                            float* __restrict__ inv_ni, float* __restrict__ inv_nj,
                            float* __restrict__ diag, float* __restrict__ rowsum) {
    const int row = blockIdx.x;
    const int t = threadIdx.x;                 // 128 threads, 4 elems each
    const float4 a = ((const float4*)(xi + (size_t)row * DIM))[t];
    const float4 b = ((const float4*)(xj + (size_t)row * DIM))[t];

    float ssi = a.x*a.x + a.y*a.y + a.z*a.z + a.w*a.w;
    float ssj = b.x*b.x + b.y*b.y + b.z*b.z + b.w*b.w;
    float dot = a.x*b.x + a.y*b.y + a.z*b.z + a.w*b.w;

    ushort4 av = { f2bf(a.x), f2bf(a.y), f2bf(a.z), f2bf(a.w) };
    ushort4 bv = { f2bf(b.x), f2bf(b.y), f2bf(b.z), f2bf(b.w) };
    ((ushort4*)(xib + (size_t)row * DIM))[t] = av;
    ((ushort4*)(xjb + (size_t)row * DIM))[t] = bv;

    #pragma unroll
    for (int m = 32; m >= 1; m >>= 1) {
        ssi += __shfl_xor(ssi, m, 64);
        ssj += __shfl_xor(ssj, m, 64);
        dot += __shfl_xor(dot, m, 64);
    }
    __shared__ float red[6];
    const int wave = t >> 6, lane = t & 63;
    if (lane == 0) { red[wave*3+0] = ssi; red[wave*3+1] = ssj; red[wave*3+2] = dot; }
    __syncthreads();
    if (t == 0) {
        float si = red[0] + red[3];
        float sj = red[1] + red[4];
        float d  = red[2] + red[5];
        float ini = rsqrtf(fmaxf(si, 1e-30f));
        float inj = rsqrtf(fmaxf(sj, 1e-30f));
        inv_ni[row] = ini;
        inv_nj[row] = inj;
        diag[row] = d * ini * inj;
        rowsum[row] = 0.0f;
    }
}

// Fused NT-GEMM + exp + row-sum. R7's winning structure (simple 2-barrier
// loop, TLP-hidden latency, proven 2-way chunk swizzle, both operands
// staged via coalesced global_load_lds) at 2x LDS-read intensity:
// block 128M x 256N, 4 waves (1M x 4N), wave tile 128x64 of 16x16x32
// frags (acc 8x4 f32x4 = 128 regs; af[8]+bg[4] = 12 b128 reads per kk).
__global__ __launch_bounds__(256, 2)
void gemm_rowsum(const u16* __restrict__ A, const u16* __restrict__ B,
                 const float* __restrict__ inv_ni, const float* __restrict__ inv_nj,
                 float* __restrict__ rowsum) {
    __shared__ __align__(16) u16 ldsA[BM * BK];   // 16 KB
    __shared__ __align__(16) u16 ldsB[BN * BK];   // 32 KB

    const int tid = threadIdx.x;
    // XCD-aware, L2-aware: concurrent ~64 blocks/XCD = 8 row-panels x 8
    // col-panels -> A 1MB + B 2MB = 3MB < 4MB per-XCD L2.
    const int orig = blockIdx.x;                  // 0..2047
    const int xcd = orig & 7, kidx = orig >> 3;   // kidx 0..255
    const int by = xcd * 8 + (kidx & 7);          // 0..63
    const int bx = kidx >> 3;                     // 0..31
    const int row0 = by * BM, col0 = bx * BN;

    // ---- staging: pass i covers row (i*32 + (tid>>3)), phys chunk tid&7 ----
    // LDS byte = i*4096 + tid*16 (linear); global logical chunk = phys ^ (row&7)
    // (row&7 invariant across passes since 32 % 8 == 0). A: 4 passes, B: 8.
    const int st_row = tid >> 3;                        // 0..31
    const int st_lc  = (tid & 7) ^ (st_row & 7);        // logical 16B k-chunk
    const u16* gA = A + (size_t)(row0 + st_row) * DIM + st_lc * 8;
    const u16* gB = B + (size_t)(col0 + st_row) * DIM + st_lc * 8;
    char* const dA = (char*)ldsA + tid * 16;
    char* const dB = (char*)ldsB + tid * 16;

    // ---- fragment reads (16x16x32, R7-verified 2-way pattern) ----
    const int lane = tid & 63;
    const int lr = lane & 15, lk = lane >> 4, sw = lr & 7;
    const int wn = tid >> 6;                            // 4 waves across N
    // af[m]: row = m*16 + lr (m=0..7); bg[n]: row = wn*64 + n*16 + lr
    const char* const aR = (const char*)ldsA + lr * 128;
    const char* const bR = (const char*)ldsB + (wn * 64 + lr) * 128;

    f32x4 acc[8][4] = {};

    #pragma unroll 1
    for (int t = 0; t < NT; ++t) {
        if (t) __syncthreads();               // prev tile's reads complete
        #pragma unroll
        for (int i = 0; i < 4; ++i)
            gload_lds16(gA + t * BK + i * 32 * DIM, dA + i * 4096);
        #pragma unroll
        for (int i = 0; i < 8; ++i)
            gload_lds16(gB + t * BK + i * 32 * DIM, dB + i * 4096);
        __syncthreads();                      // drains vmcnt; TLP fills stall

        #pragma unroll
        for (int kk = 0; kk < 2; ++kk) {
            const int cb = ((kk * 4 + lk) ^ sw) * 16;
            bf16x8 af[8], bg[4];
            #pragma unroll
            for (int n = 0; n < 4; ++n)
                bg[n] = *(const bf16x8*)(bR + n * 2048 + cb);
            #pragma unroll
            for (int m = 0; m < 8; ++m)
                af[m] = *(const bf16x8*)(aR + m * 2048 + cb);
            #pragma unroll
            for (int m = 0; m < 8; ++m)
                #pragma unroll
                for (int n = 0; n < 4; ++n)
                    acc[m][n] = __builtin_amdgcn_mfma_f32_16x16x32_bf16(
                        af[m], bg[n], acc[m][n], 0, 0, 0);
        }
    }

    // ---- epilogue: cosine scale, exp, row-reduce, one atomic per row ----
    float inj[4];
    #pragma unroll
    for (int n = 0; n < 4; ++n)
        inj[n] = inv_nj[col0 + wn * 64 + n * 16 + lr];

    #pragma unroll
    for (int m = 0; m < 8; ++m) {
        #pragma unroll
        for (int e = 0; e < 4; ++e) {
            const int row = row0 + m * 16 + lk * 4 + e;
            const float ini = inv_ni[row];
            float s = 0.0f;
            #pragma unroll
            for (int n = 0; n < 4; ++n)
                s += __expf(acc[m][n][e] * ini * inj[n]);
            s += __shfl_xor(s, 1, 64);
            s += __shfl_xor(s, 2, 64);
            s += __shfl_xor(s, 4, 64);
            s += __shfl_xor(s, 8, 64);
            if (lr == 0)
                atomicAdd(&rowsum[row], s);
        }
    }
}

__global__ void finalize(const float* __restrict__ rowsum,
                         const float* __restrict__ diag,
                         float* __restrict__ out) {
    const float E1 = 2.7182818284590452f;  // exp(1/TAU)
    float acc = 0.0f;
    for (int i = threadIdx.x; i < NR; i += 256)
        acc += __logf(rowsum[i] - E1) - diag[i];
    #pragma unroll
    for (int m = 32; m >= 1; m >>= 1)
        acc += __shfl_xor(acc, m, 64);
    __shared__ float red[4];
    const int wave = threadIdx.x >> 6, lane = threadIdx.x & 63;
    if (lane == 0) red[wave] = acc;
    __syncthreads();
    if (threadIdx.x == 0)
        out[0] = (red[0] + red[1] + red[2] + red[3]) * (1.0f / NR);
}

extern "C" void kernel_launch(void* const* d_in, const int* in_sizes, int n_in,
                              void* d_out, int out_size, void* d_ws, size_t ws_size,
                              hipStream_t stream) {
    const float* xi = (const float*)d_in[0];
    const float* xj = (const float*)d_in[1];

    char* ws = (char*)d_ws;
    u16* xib = (u16*)ws;                                // 8 MB
    u16* xjb = xib + (size_t)NR * DIM;                  // 8 MB
    float* inv_ni = (float*)(xjb + (size_t)NR * DIM);   // 32 KB
    float* inv_nj = inv_ni + NR;
    float* diag   = inv_nj + NR;
    float* rowsum = diag + NR;

    prep_kernel<<<NR, 128, 0, stream>>>(xi, xj, xib, xjb, inv_ni, inv_nj, diag, rowsum);
    gemm_rowsum<<<(NR / BM) * (NR / BN), 256, 0, stream>>>(xib, xjb, inv_ni, inv_nj, rowsum);
    finalize<<<1, 256, 0, stream>>>(rowsum, diag, (float*)d_out);
}